// Round 7
// baseline (246.342 us; speedup 1.0000x reference)
//
#include <hip/hip_runtime.h>

#define NN 50000
#define EE 800000
#define DD 96
#define NB 196          // ceil(NN/256) scan blocks

// Windowed scatter params (k_count / k_fill): register-cache EPT edges per
// thread, sweep NPASS dst-windows so scattered writes/atomics stay L2-local.
#define EPT 4
#define NPASS 8
#define WIN ((NN + NPASS - 1) / NPASS)          // 6250
#define FBLK ((EE + 256 * EPT - 1) / (256 * EPT))  // 782 blocks

// Harness passes integer inputs as int32 — edge_index is const int* (2,E).

// ---------------- CSR build (by dst), shared by both layers -----------------

__global__ void k_zero(int* __restrict__ cnt) {
    int i = blockIdx.x * blockDim.x + threadIdx.x;
    if (i < NN) cnt[i] = 0;
}

__global__ __launch_bounds__(256) void k_count(const int* __restrict__ ei,
                                               int* __restrict__ cnt) {
    int t = threadIdx.x;
    int d[EPT];
#pragma unroll
    for (int k = 0; k < EPT; ++k) {
        int e = blockIdx.x * 256 * EPT + k * 256 + t;   // coalesced per k
        d[k] = (e < EE) ? ei[EE + e] : 0x7fffffff;
    }
    for (int pass = 0; pass < NPASS; ++pass) {
        int lo = pass * WIN, hi = lo + WIN;
#pragma unroll
        for (int k = 0; k < EPT; ++k)
            if (d[k] >= lo && d[k] < hi) atomicAdd(&cnt[d[k]], 1);
    }
}

// Level 1: per-block exclusive scan of 256 counts; block total -> bsum.
__global__ __launch_bounds__(256) void k_bscan(const int* __restrict__ cnt,
                                               int* __restrict__ part,
                                               int* __restrict__ bsum) {
    __shared__ int sh[256];
    int t = threadIdx.x;
    int g = blockIdx.x * 256 + t;
    int v = (g < NN) ? cnt[g] : 0;
    sh[t] = v;
    __syncthreads();
    for (int off = 1; off < 256; off <<= 1) {
        int u = (t >= off) ? sh[t - off] : 0;
        __syncthreads();
        sh[t] += u;
        __syncthreads();
    }
    if (g < NN) part[g] = sh[t] - v;          // exclusive within block
    if (t == 255) bsum[blockIdx.x] = sh[255]; // block total
}

// Level 2: exclusive scan of the NB block sums (single tiny block).
__global__ __launch_bounds__(256) void k_scan2(int* __restrict__ bsum) {
    __shared__ int sh[256];
    int t = threadIdx.x;
    int v = (t < NB) ? bsum[t] : 0;
    sh[t] = v;
    __syncthreads();
    for (int off = 1; off < 256; off <<= 1) {
        int u = (t >= off) ? sh[t - off] : 0;
        __syncthreads();
        sh[t] += u;
        __syncthreads();
    }
    if (t < NB) bsum[t] = sh[t] - v;          // exclusive block offsets
}

// Level 3: rp = part + bsum[blk]; dinv = rsqrt(deg+1); re-zero part (cursor).
__global__ void k_final(const int* __restrict__ cnt, int* __restrict__ part,
                        const int* __restrict__ bsum, int* __restrict__ rp,
                        float* __restrict__ dinv) {
    int i = blockIdx.x * blockDim.x + threadIdx.x;
    if (i < NN) {
        rp[i] = part[i] + bsum[i >> 8];
        dinv[i] = rsqrtf((float)(cnt[i] + 1));   // +1 self-loop
        part[i] = 0;                              // becomes fill cursor
    }
    if (i == 0) rp[NN] = EE;
}

// Windowed fill: all col/cursor traffic at any moment lands in one
// 400 KB / 25 KB window -> full-line write combining in L2.
__global__ __launch_bounds__(256) void k_fill(const int* __restrict__ ei,
                                              const int* __restrict__ rp,
                                              int* __restrict__ cursor,
                                              int* __restrict__ col) {
    int t = threadIdx.x;
    int s[EPT], d[EPT];
#pragma unroll
    for (int k = 0; k < EPT; ++k) {
        int e = blockIdx.x * 256 * EPT + k * 256 + t;   // coalesced per k
        s[k] = (e < EE) ? ei[e] : 0;
        d[k] = (e < EE) ? ei[EE + e] : 0x7fffffff;
    }
    for (int pass = 0; pass < NPASS; ++pass) {
        int lo = pass * WIN, hi = lo + WIN;
#pragma unroll
        for (int k = 0; k < EPT; ++k)
            if (d[k] >= lo && d[k] < hi) {
                int p = rp[d[k]] + atomicAdd(&cursor[d[k]], 1);
                col[p] = s[k];
            }
    }
}

// ---------------- GEMM: out[r] = dinv[r] * (in[r] @ W)  ---------------------
// 384 threads = 16 row-threads x 24 col4-groups; 32 rows per block.
// dinv pre-scaling folds the per-source norm into the GEMM epilogue so the
// pull kernel is a pure float4 sum.

__global__ __launch_bounds__(384) void k_gemm(const float* __restrict__ in,
                                              const float* __restrict__ W,
                                              const float* __restrict__ dinv,
                                              float* __restrict__ out) {
    __shared__ float Wl[DD * DD];
    __shared__ float Rl[32][DD];
    int t = threadIdx.x;
    for (int i = t; i < DD * DD; i += 384) Wl[i] = W[i];
    int row0 = blockIdx.x * 32;
    for (int i = t; i < 32 * DD; i += 384) {
        int rr = i / DD, cc = i - rr * DD;
        int r = row0 + rr;
        Rl[rr][cc] = (r < NN) ? in[r * DD + cc] : 0.f;
    }
    __syncthreads();

    int tx = t % 24;        // col group
    int ry = t / 24;        // rows ry, ry+16
    int c0 = tx * 4;
    float a0x = 0.f, a0y = 0.f, a0z = 0.f, a0w = 0.f;
    float a1x = 0.f, a1y = 0.f, a1z = 0.f, a1w = 0.f;
#pragma unroll 8
    for (int k = 0; k < DD; ++k) {
        float4 w = *(const float4*)&Wl[k * DD + c0];
        float r0 = Rl[ry][k];
        float r1 = Rl[ry + 16][k];
        a0x += r0 * w.x; a0y += r0 * w.y; a0z += r0 * w.z; a0w += r0 * w.w;
        a1x += r1 * w.x; a1y += r1 * w.y; a1z += r1 * w.z; a1w += r1 * w.w;
    }
    int r0i = row0 + ry, r1i = row0 + ry + 16;
    if (r0i < NN) {
        float s = dinv[r0i];
        *(float4*)&out[r0i * DD + c0] = make_float4(s*a0x, s*a0y, s*a0z, s*a0w);
    }
    if (r1i < NN) {
        float s = dinv[r1i];
        *(float4*)&out[r1i * DD + c0] = make_float4(s*a1x, s*a1y, s*a1z, s*a1w);
    }
}

// ---------------- pull aggregation (float4 gather, fused bias+relu) ---------
// h' rows are pre-scaled by dinv[src]; out[d] = relu(dinv[d]*(sum + self) + b).
// 384 threads = 16 nodes x 24 float4-lanes. 16B per outstanding load.

__global__ __launch_bounds__(384) void k_pull(const float4* __restrict__ h4,
                                              const int* __restrict__ rp,
                                              const int* __restrict__ col,
                                              const float* __restrict__ dinv,
                                              const float4* __restrict__ b4,
                                              float4* __restrict__ out4) {
    int c  = threadIdx.x % 24;   // float4 column
    int ny = threadIdx.x / 24;   // 0..15
    int d = blockIdx.x * 16 + ny;
    if (d >= NN) return;
    int j0 = rp[d], j1 = rp[d + 1];
    float4 a0 = {0,0,0,0}, a1 = {0,0,0,0}, a2 = {0,0,0,0}, a3 = {0,0,0,0};
    int j = j0;
    for (; j + 3 < j1; j += 4) {
        int s0 = col[j], s1 = col[j+1], s2 = col[j+2], s3 = col[j+3];
        float4 v0 = h4[s0 * 24 + c];
        float4 v1 = h4[s1 * 24 + c];
        float4 v2 = h4[s2 * 24 + c];
        float4 v3 = h4[s3 * 24 + c];
        a0.x += v0.x; a0.y += v0.y; a0.z += v0.z; a0.w += v0.w;
        a1.x += v1.x; a1.y += v1.y; a1.z += v1.z; a1.w += v1.w;
        a2.x += v2.x; a2.y += v2.y; a2.z += v2.z; a2.w += v2.w;
        a3.x += v3.x; a3.y += v3.y; a3.z += v3.z; a3.w += v3.w;
    }
    for (; j < j1; ++j) {
        float4 v = h4[col[j] * 24 + c];
        a0.x += v.x; a0.y += v.y; a0.z += v.z; a0.w += v.w;
    }
    float4 self = h4[d * 24 + c];     // self-loop (pre-scaled by dinv[d])
    float dd = dinv[d];
    float4 bb = b4[c];
    float4 r;
    r.x = fmaxf(dd * ((a0.x + a1.x) + (a2.x + a3.x) + self.x) + bb.x, 0.f);
    r.y = fmaxf(dd * ((a0.y + a1.y) + (a2.y + a3.y) + self.y) + bb.y, 0.f);
    r.z = fmaxf(dd * ((a0.z + a1.z) + (a2.z + a3.z) + self.z) + bb.z, 0.f);
    r.w = fmaxf(dd * ((a0.w + a1.w) + (a2.w + a3.w) + self.w) + bb.w, 0.f);
    out4[d * 24 + c] = r;
}

// ----------------------------------------------------------------------------

extern "C" void kernel_launch(void* const* d_in, const int* in_sizes, int n_in,
                              void* d_out, int out_size, void* d_ws, size_t ws_size,
                              hipStream_t stream) {
    const float* x  = (const float*)d_in[0];
    const int*   ei = (const int*)d_in[1];
    const float* W1 = (const float*)d_in[2];
    const float* b1 = (const float*)d_in[3];
    const float* W2 = (const float*)d_in[4];
    const float* b2 = (const float*)d_in[5];
    float* out = (float*)d_out;

    // Workspace: cnt, part/cursor, rp, col, dinv, bsum, tmp  (~23.2 MB)
    char* p = (char*)d_ws;
    int*   cnt    = (int*)p;   p += ((size_t)NN * 4 + 255) & ~(size_t)255;
    int*   part   = (int*)p;   p += ((size_t)NN * 4 + 255) & ~(size_t)255;  // doubles as fill cursor
    int*   rp     = (int*)p;   p += ((size_t)(NN + 1) * 4 + 255) & ~(size_t)255;
    int*   col    = (int*)p;   p += ((size_t)EE * 4 + 255) & ~(size_t)255;
    float* dinv   = (float*)p; p += ((size_t)NN * 4 + 255) & ~(size_t)255;
    int*   bsum   = (int*)p;   p += ((size_t)NB * 4 + 255) & ~(size_t)255;
    float* tmp    = (float*)p;                    // N*D floats (19.2 MB)

    // ---- CSR build ----
    k_zero<<<(NN + 255) / 256, 256, 0, stream>>>(cnt);
    k_count<<<FBLK, 256, 0, stream>>>(ei, cnt);
    k_bscan<<<NB, 256, 0, stream>>>(cnt, part, bsum);
    k_scan2<<<1, 256, 0, stream>>>(bsum);
    k_final<<<(NN + 255) / 256, 256, 0, stream>>>(cnt, part, bsum, rp, dinv);
    k_fill<<<FBLK, 256, 0, stream>>>(ei, rp, part, col);

    // ---- layer 1: tmp = dinv .* (x@W1) ; d_out = relu(agg(tmp)) ----
    k_gemm<<<(NN + 31) / 32, 384, 0, stream>>>(x, W1, dinv, tmp);
    k_pull<<<(NN + 15) / 16, 384, 0, stream>>>((const float4*)tmp, rp, col, dinv,
                                               (const float4*)b1, (float4*)out);

    // ---- layer 2: tmp = dinv .* (d_out@W2) ; d_out = relu(agg(tmp)) ----
    k_gemm<<<(NN + 31) / 32, 384, 0, stream>>>(out, W2, dinv, tmp);
    k_pull<<<(NN + 15) / 16, 384, 0, stream>>>((const float4*)tmp, rp, col, dinv,
                                               (const float4*)b2, (float4*)out);
}

// Round 8
// 244.367 us; speedup vs baseline: 1.0081x; 1.0081x over previous
//
#include <hip/hip_runtime.h>

#define NN 50000
#define EE 800000
#define DD 96

#define NBIN 196            // coarse bins of 256 dst nodes: bin = d >> 8
#define CE   4096           // edges per phase-1 block
#define CB   196            // ceil(EE / CE) phase-1 blocks
#define EPT2 16             // CE / 256 edges per thread
#define MB   (NBIN * CB)    // 38416 histB entries

// Harness passes integer inputs as int32 — edge_index is const int* (2,E).
// CSR build: two-level counting sort; LDS atomics only; coalesced global
// writes (round-7 lesson: cross-XCD global atomics are memory-side full-line
// RMWs -> 50+B HBM write per 4B op; windowing can't fix that).

// ---- 1a: coarse histogram per edge-chunk --------------------------------

__global__ __launch_bounds__(256) void k_hist(const int* __restrict__ ei,
                                              int* __restrict__ histB) {
    __shared__ int hist[NBIN];
    int t = threadIdx.x;
    if (t < NBIN) hist[t] = 0;
    __syncthreads();
    int e0 = blockIdx.x * CE;
#pragma unroll
    for (int k = 0; k < EPT2; ++k) {
        int e = e0 + k * 256 + t;
        if (e < EE) atomicAdd(&hist[ei[EE + e] >> 8], 1);
    }
    __syncthreads();
    if (t < NBIN) histB[t * CB + blockIdx.x] = hist[t];  // bin-major
}

// ---- 1b: exclusive scan of histB (38416, bin-major) + binbase -----------

__global__ __launch_bounds__(1024) void k_scanB(int* __restrict__ a,
                                                int* __restrict__ binbase) {
    __shared__ int part[1024];
    const int C2 = (MB + 1023) / 1024;   // 38
    int t = threadIdx.x;
    int lo = t * C2, hi = min(lo + C2, MB);
    int s = 0;
    for (int i = lo; i < hi; ++i) s += a[i];
    part[t] = s;
    __syncthreads();
    for (int off = 1; off < 1024; off <<= 1) {
        int v = (t >= off) ? part[t - off] : 0;
        __syncthreads();
        part[t] += v;
        __syncthreads();
    }
    int run = part[t] - s;               // exclusive base of this chunk
    for (int i = lo; i < hi; ++i) {
        int old = a[i];
        a[i] = run;
        if (i % CB == 0) binbase[i / CB] = run;
        run += old;
    }
    if (t == 0) binbase[NBIN] = EE;
}

// ---- 1c: bin-scatter into packed[] (LDS sort, coalesced run writes) -----

__global__ __launch_bounds__(256) void k_scatter_bins(const int* __restrict__ ei,
                                                      const int* __restrict__ histB,
                                                      int* __restrict__ packed) {
    __shared__ int hist[NBIN];
    __shared__ int lofs[NBIN + 1];
    __shared__ int cur[NBIN];
    __shared__ int sstart[NBIN];
    __shared__ int buf[CE];
    __shared__ int sh[256];
    int t = threadIdx.x;
    int e0 = blockIdx.x * CE;
    int nE = min(CE, EE - e0);

    int s[EPT2], d[EPT2];
#pragma unroll
    for (int k = 0; k < EPT2; ++k) {
        int e = e0 + k * 256 + t;
        s[k] = (e < EE) ? ei[e] : 0;
        d[k] = (e < EE) ? ei[EE + e] : -1;
    }
    if (t < NBIN) hist[t] = 0;
    __syncthreads();
#pragma unroll
    for (int k = 0; k < EPT2; ++k)
        if (d[k] >= 0) atomicAdd(&hist[d[k] >> 8], 1);
    __syncthreads();
    // exclusive scan of hist[196] via 256-wide Hillis-Steele
    int v = (t < NBIN) ? hist[t] : 0;
    sh[t] = v;
    __syncthreads();
    for (int off = 1; off < 256; off <<= 1) {
        int u = (t >= off) ? sh[t - off] : 0;
        __syncthreads();
        sh[t] += u;
        __syncthreads();
    }
    if (t < NBIN) { lofs[t] = sh[t] - v; cur[t] = sh[t] - v; }
    if (t == 0) lofs[NBIN] = nE;
    if (t < NBIN) sstart[t] = histB[t * CB + blockIdx.x];
    __syncthreads();
#pragma unroll
    for (int k = 0; k < EPT2; ++k)
        if (d[k] >= 0) {
            int b = d[k] >> 8;
            int pos = atomicAdd(&cur[b], 1);
            buf[pos] = s[k] | ((d[k] & 0xFF) << 16);
        }
    __syncthreads();
    for (int i = t; i < nE; i += 256) {
        int blo = 0, bhi = NBIN;                 // find bin: lofs[b] <= i < lofs[b+1]
        while (bhi - blo > 1) {
            int mid = (blo + bhi) >> 1;
            if (lofs[mid] <= i) blo = mid; else bhi = mid;
        }
        packed[sstart[blo] + (i - lofs[blo])] = buf[i];
    }
}

// ---- 2: per-bin exact CSR (rp, dinv, col) — block owns its col window ---

__global__ __launch_bounds__(256) void k_csr(const int* __restrict__ packed,
                                             const int* __restrict__ binbase,
                                             int* __restrict__ rp,
                                             float* __restrict__ dinv,
                                             int* __restrict__ col) {
    __shared__ int h256[256];
    __shared__ int excl[256];
    __shared__ int cur[256];
    __shared__ int sh[256];
    int t = threadIdx.x;
    int b = blockIdx.x;
    int base = binbase[b];
    int nE = binbase[b + 1] - base;

    h256[t] = 0;
    __syncthreads();
    for (int i = t; i < nE; i += 256)
        atomicAdd(&h256[(packed[base + i] >> 16) & 0xFF], 1);
    __syncthreads();
    int v = h256[t];
    sh[t] = v;
    __syncthreads();
    for (int off = 1; off < 256; off <<= 1) {
        int u = (t >= off) ? sh[t - off] : 0;
        __syncthreads();
        sh[t] += u;
        __syncthreads();
    }
    excl[t] = sh[t] - v;
    cur[t] = sh[t] - v;
    int node = b * 256 + t;
    if (node <= NN) rp[node] = base + excl[t];   // node==NN lands on EE
    if (node < NN) dinv[node] = rsqrtf((float)(h256[t] + 1));  // +1 self-loop
    __syncthreads();
    for (int i = t; i < nE; i += 256) {
        int pv = packed[base + i];
        int pos = atomicAdd(&cur[(pv >> 16) & 0xFF], 1);
        col[base + pos] = pv & 0xFFFF;
    }
}

// ---------------- GEMM: out[r] = dinv[r] * (in[r] @ W)  ---------------------
// 384 threads = 16 row-threads x 24 col4-groups; 32 rows per block.

__global__ __launch_bounds__(384) void k_gemm(const float* __restrict__ in,
                                              const float* __restrict__ W,
                                              const float* __restrict__ dinv,
                                              float* __restrict__ out) {
    __shared__ float Wl[DD * DD];
    __shared__ float Rl[32][DD];
    int t = threadIdx.x;
    for (int i = t; i < DD * DD; i += 384) Wl[i] = W[i];
    int row0 = blockIdx.x * 32;
    for (int i = t; i < 32 * DD; i += 384) {
        int rr = i / DD, cc = i - rr * DD;
        int r = row0 + rr;
        Rl[rr][cc] = (r < NN) ? in[r * DD + cc] : 0.f;
    }
    __syncthreads();

    int tx = t % 24;        // col group
    int ry = t / 24;        // rows ry, ry+16
    int c0 = tx * 4;
    float a0x = 0.f, a0y = 0.f, a0z = 0.f, a0w = 0.f;
    float a1x = 0.f, a1y = 0.f, a1z = 0.f, a1w = 0.f;
#pragma unroll 8
    for (int k = 0; k < DD; ++k) {
        float4 w = *(const float4*)&Wl[k * DD + c0];
        float r0 = Rl[ry][k];
        float r1 = Rl[ry + 16][k];
        a0x += r0 * w.x; a0y += r0 * w.y; a0z += r0 * w.z; a0w += r0 * w.w;
        a1x += r1 * w.x; a1y += r1 * w.y; a1z += r1 * w.z; a1w += r1 * w.w;
    }
    int r0i = row0 + ry, r1i = row0 + ry + 16;
    if (r0i < NN) {
        float sc = dinv[r0i];
        *(float4*)&out[r0i * DD + c0] = make_float4(sc*a0x, sc*a0y, sc*a0z, sc*a0w);
    }
    if (r1i < NN) {
        float sc = dinv[r1i];
        *(float4*)&out[r1i * DD + c0] = make_float4(sc*a1x, sc*a1y, sc*a1z, sc*a1w);
    }
}

// ---------------- pull aggregation (float4 gather, fused bias+relu) ---------
// h' rows pre-scaled by dinv[src]; out[d] = relu(dinv[d]*(sum + self) + b).
// 384 threads = 16 nodes x 24 float4-lanes.

__global__ __launch_bounds__(384) void k_pull(const float4* __restrict__ h4,
                                              const int* __restrict__ rp,
                                              const int* __restrict__ col,
                                              const float* __restrict__ dinv,
                                              const float4* __restrict__ b4,
                                              float4* __restrict__ out4) {
    int c  = threadIdx.x % 24;   // float4 column
    int ny = threadIdx.x / 24;   // 0..15
    int d = blockIdx.x * 16 + ny;
    if (d >= NN) return;
    int j0 = rp[d], j1 = rp[d + 1];
    float4 a0 = {0,0,0,0}, a1 = {0,0,0,0}, a2 = {0,0,0,0}, a3 = {0,0,0,0};
    int j = j0;
    for (; j + 3 < j1; j += 4) {
        int s0 = col[j], s1 = col[j+1], s2 = col[j+2], s3 = col[j+3];
        float4 v0 = h4[s0 * 24 + c];
        float4 v1 = h4[s1 * 24 + c];
        float4 v2 = h4[s2 * 24 + c];
        float4 v3 = h4[s3 * 24 + c];
        a0.x += v0.x; a0.y += v0.y; a0.z += v0.z; a0.w += v0.w;
        a1.x += v1.x; a1.y += v1.y; a1.z += v1.z; a1.w += v1.w;
        a2.x += v2.x; a2.y += v2.y; a2.z += v2.z; a2.w += v2.w;
        a3.x += v3.x; a3.y += v3.y; a3.z += v3.z; a3.w += v3.w;
    }
    for (; j < j1; ++j) {
        float4 v = h4[col[j] * 24 + c];
        a0.x += v.x; a0.y += v.y; a0.z += v.z; a0.w += v.w;
    }
    float4 self = h4[d * 24 + c];     // self-loop (pre-scaled by dinv[d])
    float dd = dinv[d];
    float4 bb = b4[c];
    float4 r;
    r.x = fmaxf(dd * ((a0.x + a1.x) + (a2.x + a3.x) + self.x) + bb.x, 0.f);
    r.y = fmaxf(dd * ((a0.y + a1.y) + (a2.y + a3.y) + self.y) + bb.y, 0.f);
    r.z = fmaxf(dd * ((a0.z + a1.z) + (a2.z + a3.z) + self.z) + bb.z, 0.f);
    r.w = fmaxf(dd * ((a0.w + a1.w) + (a2.w + a3.w) + self.w) + bb.w, 0.f);
    out4[d * 24 + c] = r;
}

// ----------------------------------------------------------------------------

extern "C" void kernel_launch(void* const* d_in, const int* in_sizes, int n_in,
                              void* d_out, int out_size, void* d_ws, size_t ws_size,
                              hipStream_t stream) {
    const float* x  = (const float*)d_in[0];
    const int*   ei = (const int*)d_in[1];
    const float* W1 = (const float*)d_in[2];
    const float* b1 = (const float*)d_in[3];
    const float* W2 = (const float*)d_in[4];
    const float* b2 = (const float*)d_in[5];
    float* out = (float*)d_out;

    // Workspace (~23 MB): histB, binbase, rp, dinv, col, tmp.
    // packed[] aliases tmp (dead until first k_gemm).
    char* p = (char*)d_ws;
    int*   histB   = (int*)p;   p += ((size_t)MB * 4 + 255) & ~(size_t)255;
    int*   binbase = (int*)p;   p += ((size_t)(NBIN + 1) * 4 + 255) & ~(size_t)255;
    int*   rp      = (int*)p;   p += ((size_t)(NN + 1) * 4 + 255) & ~(size_t)255;
    float* dinv    = (float*)p; p += ((size_t)NN * 4 + 255) & ~(size_t)255;
    int*   col     = (int*)p;   p += ((size_t)EE * 4 + 255) & ~(size_t)255;
    float* tmp     = (float*)p;                    // N*D floats (19.2 MB)
    int*   packed  = (int*)tmp;                    // EE ints, alias

    // ---- CSR build (no global atomics) ----
    k_hist<<<CB, 256, 0, stream>>>(ei, histB);
    k_scanB<<<1, 1024, 0, stream>>>(histB, binbase);
    k_scatter_bins<<<CB, 256, 0, stream>>>(ei, histB, packed);
    k_csr<<<NBIN, 256, 0, stream>>>(packed, binbase, rp, dinv, col);

    // ---- layer 1: tmp = dinv .* (x@W1) ; d_out = relu(agg(tmp)) ----
    k_gemm<<<(NN + 31) / 32, 384, 0, stream>>>(x, W1, dinv, tmp);
    k_pull<<<(NN + 15) / 16, 384, 0, stream>>>((const float4*)tmp, rp, col, dinv,
                                               (const float4*)b1, (float4*)out);

    // ---- layer 2: tmp = dinv .* (d_out@W2) ; d_out = relu(agg(tmp)) ----
    k_gemm<<<(NN + 31) / 32, 384, 0, stream>>>(out, W2, dinv, tmp);
    k_pull<<<(NN + 15) / 16, 384, 0, stream>>>((const float4*)tmp, rp, col, dinv,
                                               (const float4*)b2, (float4*)out);
}

// Round 9
// 192.742 us; speedup vs baseline: 1.2781x; 1.2678x over previous
//
#include <hip/hip_runtime.h>

#define NN 50000
#define EE 800000
#define DD 96

#define NBIN 196            // coarse bins of 256 dst nodes: bin = d >> 8
#define CE   4096           // edges per phase-1 block
#define CB   196            // ceil(EE / CE) phase-1 blocks

#define EPT2 16             // CE / 256 edges per thread

// Harness passes integer inputs as int32 — edge_index is const int* (2,E).
// CSR build: two-level counting sort; LDS atomics only; coalesced global
// writes. Round-7 lesson: cross-XCD global atomics are memory-side full-line
// RMWs (50+B HBM write per 4B op). Round-8 lesson: single-block scans of
// >10K elements are ~60us latency holes — scan per-bin rows in parallel.

// ---- 1a: coarse histogram per edge-chunk --------------------------------

__global__ __launch_bounds__(256) void k_hist(const int* __restrict__ ei,
                                              int* __restrict__ histB) {
    __shared__ int hist[NBIN];
    int t = threadIdx.x;
    if (t < NBIN) hist[t] = 0;
    __syncthreads();
    int e0 = blockIdx.x * CE;
#pragma unroll
    for (int k = 0; k < EPT2; ++k) {
        int e = e0 + k * 256 + t;
        if (e < EE) atomicAdd(&hist[ei[EE + e] >> 8], 1);
    }
    __syncthreads();
    if (t < NBIN) histB[t * CB + blockIdx.x] = hist[t];  // bin-major
}

// ---- 1b-i: per-bin row scan (196 blocks, one row each) ------------------
// histB row -> within-bin exclusive prefix; row total -> binTot[bin].

__global__ __launch_bounds__(256) void k_scan_bins(int* __restrict__ histB,
                                                   int* __restrict__ binTot) {
    __shared__ int sh[256];
    int t = threadIdx.x;
    int b = blockIdx.x;
    int v = (t < CB) ? histB[b * CB + t] : 0;
    sh[t] = v;
    __syncthreads();
    for (int off = 1; off < 256; off <<= 1) {
        int u = (t >= off) ? sh[t - off] : 0;
        __syncthreads();
        sh[t] += u;
        __syncthreads();
    }
    if (t < CB) histB[b * CB + t] = sh[t] - v;   // exclusive within bin
    if (t == 255) binTot[b] = sh[255];           // bin total
}

// ---- 1b-ii: scan of 196 bin totals -> binbase ---------------------------

__global__ __launch_bounds__(256) void k_scan_tot(const int* __restrict__ binTot,
                                                  int* __restrict__ binbase) {
    __shared__ int sh[256];
    int t = threadIdx.x;
    int v = (t < NBIN) ? binTot[t] : 0;
    sh[t] = v;
    __syncthreads();
    for (int off = 1; off < 256; off <<= 1) {
        int u = (t >= off) ? sh[t - off] : 0;
        __syncthreads();
        sh[t] += u;
        __syncthreads();
    }
    if (t < NBIN) binbase[t] = sh[t] - v;
    if (t == 0) binbase[NBIN] = EE;
}

// ---- 1c: bin-scatter into packed[] (LDS sort, coalesced run writes) -----

__global__ __launch_bounds__(256) void k_scatter_bins(const int* __restrict__ ei,
                                                      const int* __restrict__ histB,
                                                      const int* __restrict__ binbase,
                                                      int* __restrict__ packed) {
    __shared__ int hist[NBIN];
    __shared__ int lofs[NBIN + 1];
    __shared__ int cur[NBIN];
    __shared__ int sstart[NBIN];
    __shared__ int buf[CE];
    __shared__ int sh[256];
    int t = threadIdx.x;
    int e0 = blockIdx.x * CE;
    int nE = min(CE, EE - e0);

    int s[EPT2], d[EPT2];
#pragma unroll
    for (int k = 0; k < EPT2; ++k) {
        int e = e0 + k * 256 + t;
        s[k] = (e < EE) ? ei[e] : 0;
        d[k] = (e < EE) ? ei[EE + e] : -1;
    }
    if (t < NBIN) hist[t] = 0;
    __syncthreads();
#pragma unroll
    for (int k = 0; k < EPT2; ++k)
        if (d[k] >= 0) atomicAdd(&hist[d[k] >> 8], 1);
    __syncthreads();
    // exclusive scan of hist[196] via 256-wide Hillis-Steele
    int v = (t < NBIN) ? hist[t] : 0;
    sh[t] = v;
    __syncthreads();
    for (int off = 1; off < 256; off <<= 1) {
        int u = (t >= off) ? sh[t - off] : 0;
        __syncthreads();
        sh[t] += u;
        __syncthreads();
    }
    if (t < NBIN) { lofs[t] = sh[t] - v; cur[t] = sh[t] - v; }
    if (t == 0) lofs[NBIN] = nE;
    if (t < NBIN) sstart[t] = binbase[t] + histB[t * CB + blockIdx.x];
    __syncthreads();
#pragma unroll
    for (int k = 0; k < EPT2; ++k)
        if (d[k] >= 0) {
            int b = d[k] >> 8;
            int pos = atomicAdd(&cur[b], 1);
            buf[pos] = s[k] | ((d[k] & 0xFF) << 16);
        }
    __syncthreads();
    for (int i = t; i < nE; i += 256) {
        int blo = 0, bhi = NBIN;                 // find bin: lofs[b] <= i < lofs[b+1]
        while (bhi - blo > 1) {
            int mid = (blo + bhi) >> 1;
            if (lofs[mid] <= i) blo = mid; else bhi = mid;
        }
        packed[sstart[blo] + (i - lofs[blo])] = buf[i];
    }
}

// ---- 2: per-bin exact CSR (rp, dinv, col) — block owns its col window ---

__global__ __launch_bounds__(256) void k_csr(const int* __restrict__ packed,
                                             const int* __restrict__ binbase,
                                             int* __restrict__ rp,
                                             float* __restrict__ dinv,
                                             int* __restrict__ col) {
    __shared__ int h256[256];
    __shared__ int excl[256];
    __shared__ int cur[256];
    __shared__ int sh[256];
    int t = threadIdx.x;
    int b = blockIdx.x;
    int base = binbase[b];
    int nE = binbase[b + 1] - base;

    h256[t] = 0;
    __syncthreads();
    for (int i = t; i < nE; i += 256)
        atomicAdd(&h256[(packed[base + i] >> 16) & 0xFF], 1);
    __syncthreads();
    int v = h256[t];
    sh[t] = v;
    __syncthreads();
    for (int off = 1; off < 256; off <<= 1) {
        int u = (t >= off) ? sh[t - off] : 0;
        __syncthreads();
        sh[t] += u;
        __syncthreads();
    }
    excl[t] = sh[t] - v;
    cur[t] = sh[t] - v;
    int node = b * 256 + t;
    if (node <= NN) rp[node] = base + excl[t];   // node==NN lands on EE
    if (node < NN) dinv[node] = rsqrtf((float)(h256[t] + 1));  // +1 self-loop
    __syncthreads();
    for (int i = t; i < nE; i += 256) {
        int pv = packed[base + i];
        int pos = atomicAdd(&cur[(pv >> 16) & 0xFF], 1);
        col[base + pos] = pv & 0xFFFF;
    }
}

// ---------------- GEMM: out[r] = dinv[r] * (in[r] @ W)  ---------------------
// 384 threads = 16 row-threads x 24 col4-groups; 32 rows per block.

__global__ __launch_bounds__(384) void k_gemm(const float* __restrict__ in,
                                              const float* __restrict__ W,
                                              const float* __restrict__ dinv,
                                              float* __restrict__ out) {
    __shared__ float Wl[DD * DD];
    __shared__ float Rl[32][DD];
    int t = threadIdx.x;
    for (int i = t; i < DD * DD; i += 384) Wl[i] = W[i];
    int row0 = blockIdx.x * 32;
    for (int i = t; i < 32 * DD; i += 384) {
        int rr = i / DD, cc = i - rr * DD;
        int r = row0 + rr;
        Rl[rr][cc] = (r < NN) ? in[r * DD + cc] : 0.f;
    }
    __syncthreads();

    int tx = t % 24;        // col group
    int ry = t / 24;        // rows ry, ry+16
    int c0 = tx * 4;
    float a0x = 0.f, a0y = 0.f, a0z = 0.f, a0w = 0.f;
    float a1x = 0.f, a1y = 0.f, a1z = 0.f, a1w = 0.f;
#pragma unroll 8
    for (int k = 0; k < DD; ++k) {
        float4 w = *(const float4*)&Wl[k * DD + c0];
        float r0 = Rl[ry][k];
        float r1 = Rl[ry + 16][k];
        a0x += r0 * w.x; a0y += r0 * w.y; a0z += r0 * w.z; a0w += r0 * w.w;
        a1x += r1 * w.x; a1y += r1 * w.y; a1z += r1 * w.z; a1w += r1 * w.w;
    }
    int r0i = row0 + ry, r1i = row0 + ry + 16;
    if (r0i < NN) {
        float sc = dinv[r0i];
        *(float4*)&out[r0i * DD + c0] = make_float4(sc*a0x, sc*a0y, sc*a0z, sc*a0w);
    }
    if (r1i < NN) {
        float sc = dinv[r1i];
        *(float4*)&out[r1i * DD + c0] = make_float4(sc*a1x, sc*a1y, sc*a1z, sc*a1w);
    }
}

// ---------------- pull aggregation (float4 gather, fused bias+relu) ---------
// h' rows pre-scaled by dinv[src]; out[d] = relu(dinv[d]*(sum + self) + b).
// 384 threads = 16 nodes x 24 float4-lanes.

__global__ __launch_bounds__(384) void k_pull(const float4* __restrict__ h4,
                                              const int* __restrict__ rp,
                                              const int* __restrict__ col,
                                              const float* __restrict__ dinv,
                                              const float4* __restrict__ b4,
                                              float4* __restrict__ out4) {
    int c  = threadIdx.x % 24;   // float4 column
    int ny = threadIdx.x / 24;   // 0..15
    int d = blockIdx.x * 16 + ny;
    if (d >= NN) return;
    int j0 = rp[d], j1 = rp[d + 1];
    float4 a0 = {0,0,0,0}, a1 = {0,0,0,0}, a2 = {0,0,0,0}, a3 = {0,0,0,0};
    int j = j0;
    for (; j + 3 < j1; j += 4) {
        int s0 = col[j], s1 = col[j+1], s2 = col[j+2], s3 = col[j+3];
        float4 v0 = h4[s0 * 24 + c];
        float4 v1 = h4[s1 * 24 + c];
        float4 v2 = h4[s2 * 24 + c];
        float4 v3 = h4[s3 * 24 + c];
        a0.x += v0.x; a0.y += v0.y; a0.z += v0.z; a0.w += v0.w;
        a1.x += v1.x; a1.y += v1.y; a1.z += v1.z; a1.w += v1.w;
        a2.x += v2.x; a2.y += v2.y; a2.z += v2.z; a2.w += v2.w;
        a3.x += v3.x; a3.y += v3.y; a3.z += v3.z; a3.w += v3.w;
    }
    for (; j < j1; ++j) {
        float4 v = h4[col[j] * 24 + c];
        a0.x += v.x; a0.y += v.y; a0.z += v.z; a0.w += v.w;
    }
    float4 self = h4[d * 24 + c];     // self-loop (pre-scaled by dinv[d])
    float dd = dinv[d];
    float4 bb = b4[c];
    float4 r;
    r.x = fmaxf(dd * ((a0.x + a1.x) + (a2.x + a3.x) + self.x) + bb.x, 0.f);
    r.y = fmaxf(dd * ((a0.y + a1.y) + (a2.y + a3.y) + self.y) + bb.y, 0.f);
    r.z = fmaxf(dd * ((a0.z + a1.z) + (a2.z + a3.z) + self.z) + bb.z, 0.f);
    r.w = fmaxf(dd * ((a0.w + a1.w) + (a2.w + a3.w) + self.w) + bb.w, 0.f);
    out4[d * 24 + c] = r;
}

// ----------------------------------------------------------------------------

extern "C" void kernel_launch(void* const* d_in, const int* in_sizes, int n_in,
                              void* d_out, int out_size, void* d_ws, size_t ws_size,
                              hipStream_t stream) {
    const float* x  = (const float*)d_in[0];
    const int*   ei = (const int*)d_in[1];
    const float* W1 = (const float*)d_in[2];
    const float* b1 = (const float*)d_in[3];
    const float* W2 = (const float*)d_in[4];
    const float* b2 = (const float*)d_in[5];
    float* out = (float*)d_out;

    // Workspace (~23 MB): histB, binTot, binbase, rp, dinv, col, tmp.
    // packed[] aliases tmp (dead until first k_gemm).
    char* p = (char*)d_ws;
    int*   histB   = (int*)p;   p += ((size_t)NBIN * CB * 4 + 255) & ~(size_t)255;
    int*   binTot  = (int*)p;   p += ((size_t)NBIN * 4 + 255) & ~(size_t)255;
    int*   binbase = (int*)p;   p += ((size_t)(NBIN + 1) * 4 + 255) & ~(size_t)255;
    int*   rp      = (int*)p;   p += ((size_t)(NN + 1) * 4 + 255) & ~(size_t)255;
    float* dinv    = (float*)p; p += ((size_t)NN * 4 + 255) & ~(size_t)255;
    int*   col     = (int*)p;   p += ((size_t)EE * 4 + 255) & ~(size_t)255;
    float* tmp     = (float*)p;                    // N*D floats (19.2 MB)
    int*   packed  = (int*)tmp;                    // EE ints, alias

    // ---- CSR build (no global atomics, no serial scans) ----
    k_hist<<<CB, 256, 0, stream>>>(ei, histB);
    k_scan_bins<<<NBIN, 256, 0, stream>>>(histB, binTot);
    k_scan_tot<<<1, 256, 0, stream>>>(binTot, binbase);
    k_scatter_bins<<<CB, 256, 0, stream>>>(ei, histB, binbase, packed);
    k_csr<<<NBIN, 256, 0, stream>>>(packed, binbase, rp, dinv, col);

    // ---- layer 1: tmp = dinv .* (x@W1) ; d_out = relu(agg(tmp)) ----
    k_gemm<<<(NN + 31) / 32, 384, 0, stream>>>(x, W1, dinv, tmp);
    k_pull<<<(NN + 15) / 16, 384, 0, stream>>>((const float4*)tmp, rp, col, dinv,
                                               (const float4*)b1, (float4*)out);

    // ---- layer 2: tmp = dinv .* (d_out@W2) ; d_out = relu(agg(tmp)) ----
    k_gemm<<<(NN + 31) / 32, 384, 0, stream>>>(out, W2, dinv, tmp);
    k_pull<<<(NN + 15) / 16, 384, 0, stream>>>((const float4*)tmp, rp, col, dinv,
                                               (const float4*)b2, (float4*)out);
}

// Round 10
// 162.123 us; speedup vs baseline: 1.5195x; 1.1889x over previous
//
#include <hip/hip_runtime.h>
#include <hip/hip_fp16.h>

#define NN 50000
#define EE 800000
#define DD 96

#define NBIN 196            // coarse bins of 256 dst nodes: bin = d >> 8
#define CE   4096           // edges per phase-1 block
#define CB   196            // ceil(EE / CE) phase-1 blocks
#define EPT2 16             // CE / 256 edges per thread

// Harness passes integer inputs as int32 — edge_index is const int* (2,E).
// Lessons: (r7) cross-XCD global atomics = memory-side full-line RMW, ~50B
// HBM write per 4B op -> CSR build uses LDS-only atomics + coalesced writes.
// (r8) single-block scans of >10K elems are ~60us latency holes -> per-bin
// parallel scans. (r10) gather traffic ~ E * row_bytes -> stage h' in fp16.

// ---- 1a: coarse histogram per edge-chunk --------------------------------

__global__ __launch_bounds__(256) void k_hist(const int* __restrict__ ei,
                                              int* __restrict__ histB) {
    __shared__ int hist[NBIN];
    int t = threadIdx.x;
    if (t < NBIN) hist[t] = 0;
    __syncthreads();
    int e0 = blockIdx.x * CE;
#pragma unroll
    for (int k = 0; k < EPT2; ++k) {
        int e = e0 + k * 256 + t;
        if (e < EE) atomicAdd(&hist[ei[EE + e] >> 8], 1);
    }
    __syncthreads();
    if (t < NBIN) histB[t * CB + blockIdx.x] = hist[t];  // bin-major
}

// ---- 1b-i: per-bin row scan (196 blocks, one row each) ------------------

__global__ __launch_bounds__(256) void k_scan_bins(int* __restrict__ histB,
                                                   int* __restrict__ binTot) {
    __shared__ int sh[256];
    int t = threadIdx.x;
    int b = blockIdx.x;
    int v = (t < CB) ? histB[b * CB + t] : 0;
    sh[t] = v;
    __syncthreads();
    for (int off = 1; off < 256; off <<= 1) {
        int u = (t >= off) ? sh[t - off] : 0;
        __syncthreads();
        sh[t] += u;
        __syncthreads();
    }
    if (t < CB) histB[b * CB + t] = sh[t] - v;   // exclusive within bin
    if (t == 255) binTot[b] = sh[255];           // bin total
}

// ---- 1b-ii: scan of 196 bin totals -> binbase ---------------------------

__global__ __launch_bounds__(256) void k_scan_tot(const int* __restrict__ binTot,
                                                  int* __restrict__ binbase) {
    __shared__ int sh[256];
    int t = threadIdx.x;
    int v = (t < NBIN) ? binTot[t] : 0;
    sh[t] = v;
    __syncthreads();
    for (int off = 1; off < 256; off <<= 1) {
        int u = (t >= off) ? sh[t - off] : 0;
        __syncthreads();
        sh[t] += u;
        __syncthreads();
    }
    if (t < NBIN) binbase[t] = sh[t] - v;
    if (t == 0) binbase[NBIN] = EE;
}

// ---- 1c: bin-scatter into packed[] (LDS sort, coalesced run writes) -----

__global__ __launch_bounds__(256) void k_scatter_bins(const int* __restrict__ ei,
                                                      const int* __restrict__ histB,
                                                      const int* __restrict__ binbase,
                                                      int* __restrict__ packed) {
    __shared__ int hist[NBIN];
    __shared__ int lofs[NBIN + 1];
    __shared__ int cur[NBIN];
    __shared__ int sstart[NBIN];
    __shared__ int buf[CE];
    __shared__ int sh[256];
    int t = threadIdx.x;
    int e0 = blockIdx.x * CE;
    int nE = min(CE, EE - e0);

    int s[EPT2], d[EPT2];
#pragma unroll
    for (int k = 0; k < EPT2; ++k) {
        int e = e0 + k * 256 + t;
        s[k] = (e < EE) ? ei[e] : 0;
        d[k] = (e < EE) ? ei[EE + e] : -1;
    }
    if (t < NBIN) hist[t] = 0;
    __syncthreads();
#pragma unroll
    for (int k = 0; k < EPT2; ++k)
        if (d[k] >= 0) atomicAdd(&hist[d[k] >> 8], 1);
    __syncthreads();
    int v = (t < NBIN) ? hist[t] : 0;
    sh[t] = v;
    __syncthreads();
    for (int off = 1; off < 256; off <<= 1) {
        int u = (t >= off) ? sh[t - off] : 0;
        __syncthreads();
        sh[t] += u;
        __syncthreads();
    }
    if (t < NBIN) { lofs[t] = sh[t] - v; cur[t] = sh[t] - v; }
    if (t == 0) lofs[NBIN] = nE;
    if (t < NBIN) sstart[t] = binbase[t] + histB[t * CB + blockIdx.x];
    __syncthreads();
#pragma unroll
    for (int k = 0; k < EPT2; ++k)
        if (d[k] >= 0) {
            int b = d[k] >> 8;
            int pos = atomicAdd(&cur[b], 1);
            buf[pos] = s[k] | ((d[k] & 0xFF) << 16);
        }
    __syncthreads();
    for (int i = t; i < nE; i += 256) {
        int blo = 0, bhi = NBIN;                 // find bin: lofs[b] <= i < lofs[b+1]
        while (bhi - blo > 1) {
            int mid = (blo + bhi) >> 1;
            if (lofs[mid] <= i) blo = mid; else bhi = mid;
        }
        packed[sstart[blo] + (i - lofs[blo])] = buf[i];
    }
}

// ---- 2: per-bin exact CSR (rp, dinv, col) — block owns its col window ---

__global__ __launch_bounds__(256) void k_csr(const int* __restrict__ packed,
                                             const int* __restrict__ binbase,
                                             int* __restrict__ rp,
                                             float* __restrict__ dinv,
                                             int* __restrict__ col) {
    __shared__ int h256[256];
    __shared__ int excl[256];
    __shared__ int cur[256];
    __shared__ int sh[256];
    int t = threadIdx.x;
    int b = blockIdx.x;
    int base = binbase[b];
    int nE = binbase[b + 1] - base;

    h256[t] = 0;
    __syncthreads();
    for (int i = t; i < nE; i += 256)
        atomicAdd(&h256[(packed[base + i] >> 16) & 0xFF], 1);
    __syncthreads();
    int v = h256[t];
    sh[t] = v;
    __syncthreads();
    for (int off = 1; off < 256; off <<= 1) {
        int u = (t >= off) ? sh[t - off] : 0;
        __syncthreads();
        sh[t] += u;
        __syncthreads();
    }
    excl[t] = sh[t] - v;
    cur[t] = sh[t] - v;
    int node = b * 256 + t;
    if (node <= NN) rp[node] = base + excl[t];   // node==NN lands on EE
    if (node < NN) dinv[node] = rsqrtf((float)(h256[t] + 1));  // +1 self-loop
    __syncthreads();
    for (int i = t; i < nE; i += 256) {
        int pv = packed[base + i];
        int pos = atomicAdd(&cur[(pv >> 16) & 0xFF], 1);
        col[base + pos] = pv & 0xFFFF;
    }
}

// ---------------- GEMM: hout[r] = fp16( dinv[r] * (in[r] @ W) ) -------------
// 384 threads = 16 row-threads x 24 col4-groups; 32 rows per block.
// fp16 staging halves both GEMM write traffic and pull gather traffic;
// added error ~5e-4 << 9.5e-3 threshold.

__global__ __launch_bounds__(384) void k_gemm(const float* __restrict__ in,
                                              const float* __restrict__ W,
                                              const float* __restrict__ dinv,
                                              __half* __restrict__ hout) {
    __shared__ float Wl[DD * DD];
    __shared__ float Rl[32][DD];
    int t = threadIdx.x;
    for (int i = t; i < DD * DD; i += 384) Wl[i] = W[i];
    int row0 = blockIdx.x * 32;
    for (int i = t; i < 32 * DD; i += 384) {
        int rr = i / DD, cc = i - rr * DD;
        int r = row0 + rr;
        Rl[rr][cc] = (r < NN) ? in[r * DD + cc] : 0.f;
    }
    __syncthreads();

    int tx = t % 24;        // col group
    int ry = t / 24;        // rows ry, ry+16
    int c0 = tx * 4;
    float a0x = 0.f, a0y = 0.f, a0z = 0.f, a0w = 0.f;
    float a1x = 0.f, a1y = 0.f, a1z = 0.f, a1w = 0.f;
#pragma unroll 8
    for (int k = 0; k < DD; ++k) {
        float4 w = *(const float4*)&Wl[k * DD + c0];
        float r0 = Rl[ry][k];
        float r1 = Rl[ry + 16][k];
        a0x += r0 * w.x; a0y += r0 * w.y; a0z += r0 * w.z; a0w += r0 * w.w;
        a1x += r1 * w.x; a1y += r1 * w.y; a1z += r1 * w.z; a1w += r1 * w.w;
    }
    int r0i = row0 + ry, r1i = row0 + ry + 16;
    if (r0i < NN) {
        float sc = dinv[r0i];
        __half h[4];
        h[0] = __float2half_rn(sc * a0x); h[1] = __float2half_rn(sc * a0y);
        h[2] = __float2half_rn(sc * a0z); h[3] = __float2half_rn(sc * a0w);
        *(uint2*)&hout[r0i * DD + c0] = *(uint2*)h;
    }
    if (r1i < NN) {
        float sc = dinv[r1i];
        __half h[4];
        h[0] = __float2half_rn(sc * a1x); h[1] = __float2half_rn(sc * a1y);
        h[2] = __float2half_rn(sc * a1z); h[3] = __float2half_rn(sc * a1w);
        *(uint2*)&hout[r1i * DD + c0] = *(uint2*)h;
    }
}

// ---------------- pull aggregation (fp16 gather, fused bias+relu) -----------
// h' rows pre-scaled by dinv[src], fp16; out[d] = relu(dinv[d]*(sum+self)+b).
// 384 threads = 32 nodes x 12 half8-lanes; 16 B per outstanding load.

__global__ __launch_bounds__(384) void k_pull(const __half* __restrict__ h2,
                                              const int* __restrict__ rp,
                                              const int* __restrict__ col,
                                              const float* __restrict__ dinv,
                                              const float* __restrict__ b,
                                              float* __restrict__ out) {
    int c  = threadIdx.x % 12;   // half8 column
    int ny = threadIdx.x / 12;   // 0..31
    int d = blockIdx.x * 32 + ny;
    if (d >= NN) return;
    const uint4* h4 = (const uint4*)h2;   // row stride 12

    union U { uint4 u; __half2 h[4]; };
    float2 aA[4] = {{0,0},{0,0},{0,0},{0,0}};
    float2 aB[4] = {{0,0},{0,0},{0,0},{0,0}};

    int j0 = rp[d], j1 = rp[d + 1];
    int j = j0;
    for (; j + 3 < j1; j += 4) {
        int s0 = col[j], s1 = col[j+1], s2 = col[j+2], s3 = col[j+3];
        U v0, v1, v2, v3;
        v0.u = h4[s0 * 12 + c];
        v1.u = h4[s1 * 12 + c];
        v2.u = h4[s2 * 12 + c];
        v3.u = h4[s3 * 12 + c];
#pragma unroll
        for (int k = 0; k < 4; ++k) {
            float2 f0 = __half22float2(v0.h[k]);
            float2 f1 = __half22float2(v1.h[k]);
            float2 f2 = __half22float2(v2.h[k]);
            float2 f3 = __half22float2(v3.h[k]);
            aA[k].x += f0.x + f1.x; aA[k].y += f0.y + f1.y;
            aB[k].x += f2.x + f3.x; aB[k].y += f2.y + f3.y;
        }
    }
    for (; j < j1; ++j) {
        U v; v.u = h4[col[j] * 12 + c];
#pragma unroll
        for (int k = 0; k < 4; ++k) {
            float2 f = __half22float2(v.h[k]);
            aA[k].x += f.x; aA[k].y += f.y;
        }
    }
    U self; self.u = h4[d * 12 + c];      // self-loop (pre-scaled by dinv[d])
    float dd = dinv[d];
    float r[8];
#pragma unroll
    for (int k = 0; k < 4; ++k) {
        float2 fs = __half22float2(self.h[k]);
        float2 bb = ((const float2*)b)[c * 4 + k];
        r[2*k]   = fmaxf(dd * (aA[k].x + aB[k].x + fs.x) + bb.x, 0.f);
        r[2*k+1] = fmaxf(dd * (aA[k].y + aB[k].y + fs.y) + bb.y, 0.f);
    }
    float4* o4 = (float4*)&out[d * DD + c * 8];
    o4[0] = make_float4(r[0], r[1], r[2], r[3]);
    o4[1] = make_float4(r[4], r[5], r[6], r[7]);
}

// ----------------------------------------------------------------------------

extern "C" void kernel_launch(void* const* d_in, const int* in_sizes, int n_in,
                              void* d_out, int out_size, void* d_ws, size_t ws_size,
                              hipStream_t stream) {
    const float* x  = (const float*)d_in[0];
    const int*   ei = (const int*)d_in[1];
    const float* W1 = (const float*)d_in[2];
    const float* b1 = (const float*)d_in[3];
    const float* W2 = (const float*)d_in[4];
    const float* b2 = (const float*)d_in[5];
    float* out = (float*)d_out;

    // Workspace (~14 MB): histB, binTot, binbase, rp, dinv, col, tmp(fp16).
    // packed[] aliases tmp (EE ints = 3.2 MB <= 9.6 MB; dead by first gemm).
    char* p = (char*)d_ws;
    int*   histB   = (int*)p;   p += ((size_t)NBIN * CB * 4 + 255) & ~(size_t)255;
    int*   binTot  = (int*)p;   p += ((size_t)NBIN * 4 + 255) & ~(size_t)255;
    int*   binbase = (int*)p;   p += ((size_t)(NBIN + 1) * 4 + 255) & ~(size_t)255;
    int*   rp      = (int*)p;   p += ((size_t)(NN + 1) * 4 + 255) & ~(size_t)255;
    float* dinv    = (float*)p; p += ((size_t)NN * 4 + 255) & ~(size_t)255;
    int*   col     = (int*)p;   p += ((size_t)EE * 4 + 255) & ~(size_t)255;
    __half* tmp    = (__half*)p;                  // N*D halves (9.6 MB)
    int*   packed  = (int*)tmp;                   // EE ints, alias

    // ---- CSR build (no global atomics, no serial scans) ----
    k_hist<<<CB, 256, 0, stream>>>(ei, histB);
    k_scan_bins<<<NBIN, 256, 0, stream>>>(histB, binTot);
    k_scan_tot<<<1, 256, 0, stream>>>(binTot, binbase);
    k_scatter_bins<<<CB, 256, 0, stream>>>(ei, histB, binbase, packed);
    k_csr<<<NBIN, 256, 0, stream>>>(packed, binbase, rp, dinv, col);

    // ---- layer 1: tmp = fp16(dinv .* (x@W1)) ; d_out = relu(agg(tmp)) ----
    k_gemm<<<(NN + 31) / 32, 384, 0, stream>>>(x, W1, dinv, tmp);
    k_pull<<<(NN + 31) / 32, 384, 0, stream>>>(tmp, rp, col, dinv, b1, out);

    // ---- layer 2: tmp = fp16(dinv .* (d_out@W2)) ; d_out = relu(agg(tmp)) ----
    k_gemm<<<(NN + 31) / 32, 384, 0, stream>>>(out, W2, dinv, tmp);
    k_pull<<<(NN + 31) / 32, 384, 0, stream>>>(tmp, rp, col, dinv, b2, out);
}

// Round 11
// 146.816 us; speedup vs baseline: 1.6779x; 1.1043x over previous
//
#include <hip/hip_runtime.h>
#include <hip/hip_fp16.h>

#define NN 50000
#define EE 800000
#define DD 96

#define NBIN 196            // coarse bins of 256 dst nodes: bin = d >> 8
#define CE   4096           // edges per phase-1 block
#define CB   196            // ceil(EE / CE) phase-1 blocks
#define EPT2 16             // CE / 256 edges per thread

// Harness passes integer inputs as int32 — edge_index is const int* (2,E).
// Lessons: (r7) cross-XCD global atomics = memory-side full-line RMW ->
// LDS-only atomics + coalesced writes. (r8) single-block scans of >10K elems
// are ~60us latency holes -> per-bin parallel scans. (r10) gather traffic ~
// E*row_bytes -> fp16 staging. (r11) GCN is linear: aggregate-then-transform
// fuses the whole layer into one kernel.

// ---- 1a: coarse histogram per edge-chunk --------------------------------

__global__ __launch_bounds__(256) void k_hist(const int* __restrict__ ei,
                                              int* __restrict__ histB) {
    __shared__ int hist[NBIN];
    int t = threadIdx.x;
    if (t < NBIN) hist[t] = 0;
    __syncthreads();
    int e0 = blockIdx.x * CE;
#pragma unroll
    for (int k = 0; k < EPT2; ++k) {
        int e = e0 + k * 256 + t;
        if (e < EE) atomicAdd(&hist[ei[EE + e] >> 8], 1);
    }
    __syncthreads();
    if (t < NBIN) histB[t * CB + blockIdx.x] = hist[t];  // bin-major
}

// ---- 1b-i: per-bin row scan (196 blocks, one row each) ------------------

__global__ __launch_bounds__(256) void k_scan_bins(int* __restrict__ histB,
                                                   int* __restrict__ binTot) {
    __shared__ int sh[256];
    int t = threadIdx.x;
    int b = blockIdx.x;
    int v = (t < CB) ? histB[b * CB + t] : 0;
    sh[t] = v;
    __syncthreads();
    for (int off = 1; off < 256; off <<= 1) {
        int u = (t >= off) ? sh[t - off] : 0;
        __syncthreads();
        sh[t] += u;
        __syncthreads();
    }
    if (t < CB) histB[b * CB + t] = sh[t] - v;   // exclusive within bin
    if (t == 255) binTot[b] = sh[255];           // bin total
}

// ---- 1b-ii: scan of 196 bin totals -> binbase ---------------------------

__global__ __launch_bounds__(256) void k_scan_tot(const int* __restrict__ binTot,
                                                  int* __restrict__ binbase) {
    __shared__ int sh[256];
    int t = threadIdx.x;
    int v = (t < NBIN) ? binTot[t] : 0;
    sh[t] = v;
    __syncthreads();
    for (int off = 1; off < 256; off <<= 1) {
        int u = (t >= off) ? sh[t - off] : 0;
        __syncthreads();
        sh[t] += u;
        __syncthreads();
    }
    if (t < NBIN) binbase[t] = sh[t] - v;
    if (t == 0) binbase[NBIN] = EE;
}

// ---- 1c: bin-scatter into packed[] (LDS sort, coalesced run writes) -----

__global__ __launch_bounds__(256) void k_scatter_bins(const int* __restrict__ ei,
                                                      const int* __restrict__ histB,
                                                      const int* __restrict__ binbase,
                                                      int* __restrict__ packed) {
    __shared__ int hist[NBIN];
    __shared__ int lofs[NBIN + 1];
    __shared__ int cur[NBIN];
    __shared__ int sstart[NBIN];
    __shared__ int buf[CE];
    __shared__ int sh[256];
    int t = threadIdx.x;
    int e0 = blockIdx.x * CE;
    int nE = min(CE, EE - e0);

    int s[EPT2], d[EPT2];
#pragma unroll
    for (int k = 0; k < EPT2; ++k) {
        int e = e0 + k * 256 + t;
        s[k] = (e < EE) ? ei[e] : 0;
        d[k] = (e < EE) ? ei[EE + e] : -1;
    }
    if (t < NBIN) hist[t] = 0;
    __syncthreads();
#pragma unroll
    for (int k = 0; k < EPT2; ++k)
        if (d[k] >= 0) atomicAdd(&hist[d[k] >> 8], 1);
    __syncthreads();
    int v = (t < NBIN) ? hist[t] : 0;
    sh[t] = v;
    __syncthreads();
    for (int off = 1; off < 256; off <<= 1) {
        int u = (t >= off) ? sh[t - off] : 0;
        __syncthreads();
        sh[t] += u;
        __syncthreads();
    }
    if (t < NBIN) { lofs[t] = sh[t] - v; cur[t] = sh[t] - v; }
    if (t == 0) lofs[NBIN] = nE;
    if (t < NBIN) sstart[t] = binbase[t] + histB[t * CB + blockIdx.x];
    __syncthreads();
#pragma unroll
    for (int k = 0; k < EPT2; ++k)
        if (d[k] >= 0) {
            int b = d[k] >> 8;
            int pos = atomicAdd(&cur[b], 1);
            buf[pos] = s[k] | ((d[k] & 0xFF) << 16);
        }
    __syncthreads();
    for (int i = t; i < nE; i += 256) {
        int blo = 0, bhi = NBIN;                 // find bin: lofs[b] <= i < lofs[b+1]
        while (bhi - blo > 1) {
            int mid = (blo + bhi) >> 1;
            if (lofs[mid] <= i) blo = mid; else bhi = mid;
        }
        packed[sstart[blo] + (i - lofs[blo])] = buf[i];
    }
}

// ---- 2: per-bin exact CSR (rp, dinv, col) — block owns its col window ---

__global__ __launch_bounds__(256) void k_csr(const int* __restrict__ packed,
                                             const int* __restrict__ binbase,
                                             int* __restrict__ rp,
                                             float* __restrict__ dinv,
                                             int* __restrict__ col) {
    __shared__ int h256[256];
    __shared__ int excl[256];
    __shared__ int cur[256];
    __shared__ int sh[256];
    int t = threadIdx.x;
    int b = blockIdx.x;
    int base = binbase[b];
    int nE = binbase[b + 1] - base;

    h256[t] = 0;
    __syncthreads();
    for (int i = t; i < nE; i += 256)
        atomicAdd(&h256[(packed[base + i] >> 16) & 0xFF], 1);
    __syncthreads();
    int v = h256[t];
    sh[t] = v;
    __syncthreads();
    for (int off = 1; off < 256; off <<= 1) {
        int u = (t >= off) ? sh[t - off] : 0;
        __syncthreads();
        sh[t] += u;
        __syncthreads();
    }
    excl[t] = sh[t] - v;
    cur[t] = sh[t] - v;
    int node = b * 256 + t;
    if (node <= NN) rp[node] = base + excl[t];   // node==NN lands on EE
    if (node < NN) dinv[node] = rsqrtf((float)(h256[t] + 1));  // +1 self-loop
    __syncthreads();
    for (int i = t; i < nE; i += 256) {
        int pv = packed[base + i];
        int pos = atomicAdd(&cur[(pv >> 16) & 0xFF], 1);
        col[base + pos] = pv & 0xFFFF;
    }
}

// ---- 3: x_h[s] = fp16(dinv[s] * x[s])  (one-time, layer-1 input) ---------

__global__ void k_cvt(const float* __restrict__ x, const float* __restrict__ dinv,
                      __half* __restrict__ xh) {
    int i = blockIdx.x * blockDim.x + threadIdx.x;   // half8 index
    if (i < NN * 12) {
        int row = i / 12;
        float sc = dinv[row];
        const float4* xx = (const float4*)x;
        float4 f0 = xx[i * 2], f1 = xx[i * 2 + 1];
        __half h[8];
        h[0] = __float2half_rn(sc * f0.x); h[1] = __float2half_rn(sc * f0.y);
        h[2] = __float2half_rn(sc * f0.z); h[3] = __float2half_rn(sc * f0.w);
        h[4] = __float2half_rn(sc * f1.x); h[5] = __float2half_rn(sc * f1.y);
        h[6] = __float2half_rn(sc * f1.z); h[7] = __float2half_rn(sc * f1.w);
        ((uint4*)xh)[i] = *(uint4*)h;
    }
}

// ---- 4: fused layer = gather(agg) -> LDS -> @W + b -> relu ----------------
// v[d] = dinv[d]*(sum_{s in in(d)} xh[s] + xh[d]);  out = relu(v @ W + b).
// FINAL=0: write acth[d] = fp16(dinv[d]*out) (pre-scaled for next gather).
// FINAL=1: write f32 out to outf.
// Phase A: 32 nodes x 12 half8-lanes (as k_pull). Phase B: 16 row-threads x
// 24 col4-groups GEMM on the LDS-staged 32x96 tile with W in LDS.

template <int FINAL>
__global__ __launch_bounds__(384) void k_fused(const __half* __restrict__ xh,
                                               const int* __restrict__ rp,
                                               const int* __restrict__ col,
                                               const float* __restrict__ dinv,
                                               const float* __restrict__ W,
                                               const float* __restrict__ b,
                                               __half* __restrict__ acth,
                                               float* __restrict__ outf) {
    __shared__ float Wl[DD * DD];
    __shared__ float Al[32][100];     // +4 pad: phase-A write bank spread
    int t = threadIdx.x;
    for (int i = t; i < DD * DD / 4; i += 384)
        ((float4*)Wl)[i] = ((const float4*)W)[i];

    int c  = t % 12;                  // half8 column
    int ny = t / 12;                  // 0..31
    int d = blockIdx.x * 32 + ny;
    const uint4* h4 = (const uint4*)xh;   // row stride 12

    if (d < NN) {
        union U { uint4 u; __half2 h[4]; };
        float2 aA[4] = {{0,0},{0,0},{0,0},{0,0}};
        float2 aB[4] = {{0,0},{0,0},{0,0},{0,0}};
        int j0 = rp[d], j1 = rp[d + 1];
        int j = j0;
        for (; j + 3 < j1; j += 4) {
            int s0 = col[j], s1 = col[j+1], s2 = col[j+2], s3 = col[j+3];
            U v0, v1, v2, v3;
            v0.u = h4[s0 * 12 + c];
            v1.u = h4[s1 * 12 + c];
            v2.u = h4[s2 * 12 + c];
            v3.u = h4[s3 * 12 + c];
#pragma unroll
            for (int k = 0; k < 4; ++k) {
                float2 f0 = __half22float2(v0.h[k]);
                float2 f1 = __half22float2(v1.h[k]);
                float2 f2 = __half22float2(v2.h[k]);
                float2 f3 = __half22float2(v3.h[k]);
                aA[k].x += f0.x + f1.x; aA[k].y += f0.y + f1.y;
                aB[k].x += f2.x + f3.x; aB[k].y += f2.y + f3.y;
            }
        }
        for (; j < j1; ++j) {
            U v; v.u = h4[col[j] * 12 + c];
#pragma unroll
            for (int k = 0; k < 4; ++k) {
                float2 f = __half22float2(v.h[k]);
                aA[k].x += f.x; aA[k].y += f.y;
            }
        }
        U self; self.u = h4[d * 12 + c];    // self-loop (pre-scaled by dinv[d])
        float dd = dinv[d];
        float v[8];
#pragma unroll
        for (int k = 0; k < 4; ++k) {
            float2 fs = __half22float2(self.h[k]);
            v[2*k]   = dd * (aA[k].x + aB[k].x + fs.x);
            v[2*k+1] = dd * (aA[k].y + aB[k].y + fs.y);
        }
        *(float4*)&Al[ny][c * 8]     = make_float4(v[0], v[1], v[2], v[3]);
        *(float4*)&Al[ny][c * 8 + 4] = make_float4(v[4], v[5], v[6], v[7]);
    }
    __syncthreads();

    // Phase B: out_tile = Al @ W + b, relu, write.
    int tx = t % 24;                  // col4 group
    int ry = t / 24;                  // rows ry, ry+16
    int c0 = tx * 4;
    float a0x = 0.f, a0y = 0.f, a0z = 0.f, a0w = 0.f;
    float a1x = 0.f, a1y = 0.f, a1z = 0.f, a1w = 0.f;
#pragma unroll 8
    for (int k = 0; k < DD; ++k) {
        float4 w = *(const float4*)&Wl[k * DD + c0];
        float r0 = Al[ry][k];
        float r1 = Al[ry + 16][k];
        a0x += r0 * w.x; a0y += r0 * w.y; a0z += r0 * w.z; a0w += r0 * w.w;
        a1x += r1 * w.x; a1y += r1 * w.y; a1z += r1 * w.z; a1w += r1 * w.w;
    }
    float4 bb = *(const float4*)&b[c0];
    int g0 = blockIdx.x * 32 + ry;
    int g1 = g0 + 16;
    float r0x = fmaxf(a0x + bb.x, 0.f), r0y = fmaxf(a0y + bb.y, 0.f);
    float r0z = fmaxf(a0z + bb.z, 0.f), r0w = fmaxf(a0w + bb.w, 0.f);
    float r1x = fmaxf(a1x + bb.x, 0.f), r1y = fmaxf(a1y + bb.y, 0.f);
    float r1z = fmaxf(a1z + bb.z, 0.f), r1w = fmaxf(a1w + bb.w, 0.f);
    if (g0 < NN) {
        if (FINAL) {
            *(float4*)&outf[g0 * DD + c0] = make_float4(r0x, r0y, r0z, r0w);
        } else {
            float sc = dinv[g0];
            __half h[4];
            h[0] = __float2half_rn(sc * r0x); h[1] = __float2half_rn(sc * r0y);
            h[2] = __float2half_rn(sc * r0z); h[3] = __float2half_rn(sc * r0w);
            *(uint2*)&acth[g0 * DD + c0] = *(uint2*)h;
        }
    }
    if (g1 < NN) {
        if (FINAL) {
            *(float4*)&outf[g1 * DD + c0] = make_float4(r1x, r1y, r1z, r1w);
        } else {
            float sc = dinv[g1];
            __half h[4];
            h[0] = __float2half_rn(sc * r1x); h[1] = __float2half_rn(sc * r1y);
            h[2] = __float2half_rn(sc * r1z); h[3] = __float2half_rn(sc * r1w);
            *(uint2*)&acth[g1 * DD + c0] = *(uint2*)h;
        }
    }
}

// ----------------------------------------------------------------------------

extern "C" void kernel_launch(void* const* d_in, const int* in_sizes, int n_in,
                              void* d_out, int out_size, void* d_ws, size_t ws_size,
                              hipStream_t stream) {
    const float* x  = (const float*)d_in[0];
    const int*   ei = (const int*)d_in[1];
    const float* W1 = (const float*)d_in[2];
    const float* b1 = (const float*)d_in[3];
    const float* W2 = (const float*)d_in[4];
    const float* b2 = (const float*)d_in[5];
    float* out = (float*)d_out;

    // Workspace (~23.0 MB): histB, binTot, binbase, rp, dinv, col, bufA, bufB.
    // packed[] aliases bufA (EE ints = 3.2 MB <= 9.6 MB; dead before k_cvt).
    char* p = (char*)d_ws;
    int*   histB   = (int*)p;   p += ((size_t)NBIN * CB * 4 + 255) & ~(size_t)255;
    int*   binTot  = (int*)p;   p += ((size_t)NBIN * 4 + 255) & ~(size_t)255;
    int*   binbase = (int*)p;   p += ((size_t)(NBIN + 1) * 4 + 255) & ~(size_t)255;
    int*   rp      = (int*)p;   p += ((size_t)(NN + 1) * 4 + 255) & ~(size_t)255;
    float* dinv    = (float*)p; p += ((size_t)NN * 4 + 255) & ~(size_t)255;
    int*   col     = (int*)p;   p += ((size_t)EE * 4 + 255) & ~(size_t)255;
    __half* bufA   = (__half*)p; p += ((size_t)NN * DD * 2 + 255) & ~(size_t)255;
    __half* bufB   = (__half*)p;                  // N*D halves (9.6 MB)
    int*   packed  = (int*)bufA;                  // EE ints, alias

    // ---- CSR build (no global atomics, no serial scans) ----
    k_hist<<<CB, 256, 0, stream>>>(ei, histB);
    k_scan_bins<<<NBIN, 256, 0, stream>>>(histB, binTot);
    k_scan_tot<<<1, 256, 0, stream>>>(binTot, binbase);
    k_scatter_bins<<<CB, 256, 0, stream>>>(ei, histB, binbase, packed);
    k_csr<<<NBIN, 256, 0, stream>>>(packed, binbase, rp, dinv, col);

    // ---- x_h = fp16(dinv .* x) ----
    k_cvt<<<(NN * 12 + 255) / 256, 256, 0, stream>>>(x, dinv, bufA);

    // ---- layer 1 (fused): bufB = fp16(dinv .* relu(agg(bufA) @ W1 + b1)) ----
    k_fused<0><<<(NN + 31) / 32, 384, 0, stream>>>(bufA, rp, col, dinv, W1, b1,
                                                   bufB, nullptr);

    // ---- layer 2 (fused): d_out = relu(agg(bufB) @ W2 + b2) ----
    k_fused<1><<<(NN + 31) / 32, 384, 0, stream>>>(bufB, rp, col, dinv, W2, b2,
                                                   nullptr, out);
}

// Round 12
// 133.651 us; speedup vs baseline: 1.8432x; 1.0985x over previous
//
#include <hip/hip_runtime.h>
#include <hip/hip_fp16.h>

#define NN 50000
#define EE 800000
#define DD 96

#define NBIN 196            // coarse bins of 256 dst nodes: bin = d >> 8
#define CE   4096           // edges per phase-1 block
#define CB   196            // ceil(EE / CE) phase-1 blocks
#define EPT2 16             // CE / 256 edges per thread

// Harness passes integer inputs as int32 — edge_index is const int* (2,E).
// Lessons: (r7) cross-XCD global atomics = memory-side full-line RMW ->
// LDS-only atomics + coalesced writes. (r8) single-block scans of >10K elems
// are ~60us latency holes -> per-bin parallel scans. (r10) gather traffic ~
// E*row_bytes -> fp16 staging. (r11) aggregate-then-transform fuses a layer
// into one kernel. (r12) fused kernel was LDS-occupancy-bound (49.6KB, 25%)
// -> W in LDS as fp16 (31.3KB total, ~5 blocks/CU).

// ---- 1a: coarse histogram per edge-chunk --------------------------------

__global__ __launch_bounds__(256) void k_hist(const int* __restrict__ ei,
                                              int* __restrict__ histB) {
    __shared__ int hist[NBIN];
    int t = threadIdx.x;
    if (t < NBIN) hist[t] = 0;
    __syncthreads();
    int e0 = blockIdx.x * CE;
#pragma unroll
    for (int k = 0; k < EPT2; ++k) {
        int e = e0 + k * 256 + t;
        if (e < EE) atomicAdd(&hist[ei[EE + e] >> 8], 1);
    }
    __syncthreads();
    if (t < NBIN) histB[t * CB + blockIdx.x] = hist[t];  // bin-major
}

// ---- 1b-i: per-bin row scan (196 blocks, one row each) ------------------

__global__ __launch_bounds__(256) void k_scan_bins(int* __restrict__ histB,
                                                   int* __restrict__ binTot) {
    __shared__ int sh[256];
    int t = threadIdx.x;
    int b = blockIdx.x;
    int v = (t < CB) ? histB[b * CB + t] : 0;
    sh[t] = v;
    __syncthreads();
    for (int off = 1; off < 256; off <<= 1) {
        int u = (t >= off) ? sh[t - off] : 0;
        __syncthreads();
        sh[t] += u;
        __syncthreads();
    }
    if (t < CB) histB[b * CB + t] = sh[t] - v;   // exclusive within bin
    if (t == 255) binTot[b] = sh[255];           // bin total
}

// ---- 1b-ii: scan of 196 bin totals -> binbase ---------------------------

__global__ __launch_bounds__(256) void k_scan_tot(const int* __restrict__ binTot,
                                                  int* __restrict__ binbase) {
    __shared__ int sh[256];
    int t = threadIdx.x;
    int v = (t < NBIN) ? binTot[t] : 0;
    sh[t] = v;
    __syncthreads();
    for (int off = 1; off < 256; off <<= 1) {
        int u = (t >= off) ? sh[t - off] : 0;
        __syncthreads();
        sh[t] += u;
        __syncthreads();
    }
    if (t < NBIN) binbase[t] = sh[t] - v;
    if (t == 0) binbase[NBIN] = EE;
}

// ---- 1c: bin-scatter into packed[] (LDS sort, coalesced run writes) -----

__global__ __launch_bounds__(256) void k_scatter_bins(const int* __restrict__ ei,
                                                      const int* __restrict__ histB,
                                                      const int* __restrict__ binbase,
                                                      int* __restrict__ packed) {
    __shared__ int hist[NBIN];
    __shared__ int lofs[NBIN + 1];
    __shared__ int cur[NBIN];
    __shared__ int sstart[NBIN];
    __shared__ int buf[CE];
    __shared__ int sh[256];
    int t = threadIdx.x;
    int e0 = blockIdx.x * CE;
    int nE = min(CE, EE - e0);

    int s[EPT2], d[EPT2];
#pragma unroll
    for (int k = 0; k < EPT2; ++k) {
        int e = e0 + k * 256 + t;
        s[k] = (e < EE) ? ei[e] : 0;
        d[k] = (e < EE) ? ei[EE + e] : -1;
    }
    if (t < NBIN) hist[t] = 0;
    __syncthreads();
#pragma unroll
    for (int k = 0; k < EPT2; ++k)
        if (d[k] >= 0) atomicAdd(&hist[d[k] >> 8], 1);
    __syncthreads();
    int v = (t < NBIN) ? hist[t] : 0;
    sh[t] = v;
    __syncthreads();
    for (int off = 1; off < 256; off <<= 1) {
        int u = (t >= off) ? sh[t - off] : 0;
        __syncthreads();
        sh[t] += u;
        __syncthreads();
    }
    if (t < NBIN) { lofs[t] = sh[t] - v; cur[t] = sh[t] - v; }
    if (t == 0) lofs[NBIN] = nE;
    if (t < NBIN) sstart[t] = binbase[t] + histB[t * CB + blockIdx.x];
    __syncthreads();
#pragma unroll
    for (int k = 0; k < EPT2; ++k)
        if (d[k] >= 0) {
            int b = d[k] >> 8;
            int pos = atomicAdd(&cur[b], 1);
            buf[pos] = s[k] | ((d[k] & 0xFF) << 16);
        }
    __syncthreads();
    for (int i = t; i < nE; i += 256) {
        int blo = 0, bhi = NBIN;                 // find bin: lofs[b] <= i < lofs[b+1]
        while (bhi - blo > 1) {
            int mid = (blo + bhi) >> 1;
            if (lofs[mid] <= i) blo = mid; else bhi = mid;
        }
        packed[sstart[blo] + (i - lofs[blo])] = buf[i];
    }
}

// ---- 2: per-bin exact CSR (rp, dinv, col) — block owns its col window ---

__global__ __launch_bounds__(256) void k_csr(const int* __restrict__ packed,
                                             const int* __restrict__ binbase,
                                             int* __restrict__ rp,
                                             float* __restrict__ dinv,
                                             int* __restrict__ col) {
    __shared__ int h256[256];
    __shared__ int excl[256];
    __shared__ int cur[256];
    __shared__ int sh[256];
    int t = threadIdx.x;
    int b = blockIdx.x;
    int base = binbase[b];
    int nE = binbase[b + 1] - base;

    h256[t] = 0;
    __syncthreads();
    for (int i = t; i < nE; i += 256)
        atomicAdd(&h256[(packed[base + i] >> 16) & 0xFF], 1);
    __syncthreads();
    int v = h256[t];
    sh[t] = v;
    __syncthreads();
    for (int off = 1; off < 256; off <<= 1) {
        int u = (t >= off) ? sh[t - off] : 0;
        __syncthreads();
        sh[t] += u;
        __syncthreads();
    }
    excl[t] = sh[t] - v;
    cur[t] = sh[t] - v;
    int node = b * 256 + t;
    if (node <= NN) rp[node] = base + excl[t];   // node==NN lands on EE
    if (node < NN) dinv[node] = rsqrtf((float)(h256[t] + 1));  // +1 self-loop
    __syncthreads();
    for (int i = t; i < nE; i += 256) {
        int pv = packed[base + i];
        int pos = atomicAdd(&cur[(pv >> 16) & 0xFF], 1);
        col[base + pos] = pv & 0xFFFF;
    }
}

// ---- 3: x_h[s] = fp16(dinv[s] * x[s])  (one-time, layer-1 input) ---------

__global__ void k_cvt(const float* __restrict__ x, const float* __restrict__ dinv,
                      __half* __restrict__ xh) {
    int i = blockIdx.x * blockDim.x + threadIdx.x;   // half8 index
    if (i < NN * 12) {
        int row = i / 12;
        float sc = dinv[row];
        const float4* xx = (const float4*)x;
        float4 f0 = xx[i * 2], f1 = xx[i * 2 + 1];
        __half h[8];
        h[0] = __float2half_rn(sc * f0.x); h[1] = __float2half_rn(sc * f0.y);
        h[2] = __float2half_rn(sc * f0.z); h[3] = __float2half_rn(sc * f0.w);
        h[4] = __float2half_rn(sc * f1.x); h[5] = __float2half_rn(sc * f1.y);
        h[6] = __float2half_rn(sc * f1.z); h[7] = __float2half_rn(sc * f1.w);
        ((uint4*)xh)[i] = *(uint4*)h;
    }
}

// ---- 4: fused layer = gather(agg) -> LDS -> @W + b -> relu ----------------
// v[d] = dinv[d]*(sum_{s in in(d)} xh[s] + xh[d]);  out = relu(v @ W + b).
// FINAL=0: write acth[d] = fp16(dinv[d]*out). FINAL=1: write f32 out.
// W staged in LDS as fp16 (18.4 KB) -> total LDS ~31.3 KB, ~5 blocks/CU.

template <int FINAL>
__global__ __launch_bounds__(384) void k_fused(const __half* __restrict__ xh,
                                               const int* __restrict__ rp,
                                               const int* __restrict__ col,
                                               const float* __restrict__ dinv,
                                               const float* __restrict__ W,
                                               const float* __restrict__ b,
                                               __half* __restrict__ acth,
                                               float* __restrict__ outf) {
    __shared__ __half Wl[DD * DD];    // fp16 W, row-major (18432 B)
    __shared__ float Al[32][100];     // +4 pad (12800 B)
    int t = threadIdx.x;
    // stage W: 8 f32 -> 8 fp16 per thread-iter (3 iters)
    for (int i = t; i < DD * DD / 8; i += 384) {
        const float4* ww = (const float4*)W;
        float4 f0 = ww[i * 2], f1 = ww[i * 2 + 1];
        __half h[8];
        h[0] = __float2half_rn(f0.x); h[1] = __float2half_rn(f0.y);
        h[2] = __float2half_rn(f0.z); h[3] = __float2half_rn(f0.w);
        h[4] = __float2half_rn(f1.x); h[5] = __float2half_rn(f1.y);
        h[6] = __float2half_rn(f1.z); h[7] = __float2half_rn(f1.w);
        ((uint4*)Wl)[i] = *(uint4*)h;
    }

    int c  = t % 12;                  // half8 column
    int ny = t / 12;                  // 0..31
    int d = blockIdx.x * 32 + ny;
    const uint4* h4 = (const uint4*)xh;   // row stride 12

    if (d < NN) {
        union U { uint4 u; __half2 h[4]; };
        float2 aA[4] = {{0,0},{0,0},{0,0},{0,0}};
        float2 aB[4] = {{0,0},{0,0},{0,0},{0,0}};
        int j0 = rp[d], j1 = rp[d + 1];
        int j = j0;
        for (; j + 3 < j1; j += 4) {
            int s0 = col[j], s1 = col[j+1], s2 = col[j+2], s3 = col[j+3];
            U v0, v1, v2, v3;
            v0.u = h4[s0 * 12 + c];
            v1.u = h4[s1 * 12 + c];
            v2.u = h4[s2 * 12 + c];
            v3.u = h4[s3 * 12 + c];
#pragma unroll
            for (int k = 0; k < 4; ++k) {
                float2 f0 = __half22float2(v0.h[k]);
                float2 f1 = __half22float2(v1.h[k]);
                float2 f2 = __half22float2(v2.h[k]);
                float2 f3 = __half22float2(v3.h[k]);
                aA[k].x += f0.x + f1.x; aA[k].y += f0.y + f1.y;
                aB[k].x += f2.x + f3.x; aB[k].y += f2.y + f3.y;
            }
        }
        for (; j < j1; ++j) {
            U v; v.u = h4[col[j] * 12 + c];
#pragma unroll
            for (int k = 0; k < 4; ++k) {
                float2 f = __half22float2(v.h[k]);
                aA[k].x += f.x; aA[k].y += f.y;
            }
        }
        U self; self.u = h4[d * 12 + c];    // self-loop (pre-scaled by dinv[d])
        float dd = dinv[d];
        float v[8];
#pragma unroll
        for (int k = 0; k < 4; ++k) {
            float2 fs = __half22float2(self.h[k]);
            v[2*k]   = dd * (aA[k].x + aB[k].x + fs.x);
            v[2*k+1] = dd * (aA[k].y + aB[k].y + fs.y);
        }
        *(float4*)&Al[ny][c * 8]     = make_float4(v[0], v[1], v[2], v[3]);
        *(float4*)&Al[ny][c * 8 + 4] = make_float4(v[4], v[5], v[6], v[7]);
    }
    __syncthreads();

    // Phase B: out_tile = Al @ W + b, relu, write.
    int tx = t % 24;                  // col4 group
    int ry = t / 24;                  // rows ry, ry+16
    int c0 = tx * 4;
    float a0x = 0.f, a0y = 0.f, a0z = 0.f, a0w = 0.f;
    float a1x = 0.f, a1y = 0.f, a1z = 0.f, a1w = 0.f;
#pragma unroll 8
    for (int k = 0; k < DD; ++k) {
        uint2 wv = *(const uint2*)&Wl[k * DD + c0];   // 4 halves
        const __half2* wh = (const __half2*)&wv;
        float2 w01 = __half22float2(wh[0]);
        float2 w23 = __half22float2(wh[1]);
        float r0 = Al[ry][k];
        float r1 = Al[ry + 16][k];
        a0x += r0 * w01.x; a0y += r0 * w01.y; a0z += r0 * w23.x; a0w += r0 * w23.y;
        a1x += r1 * w01.x; a1y += r1 * w01.y; a1z += r1 * w23.x; a1w += r1 * w23.y;
    }
    float4 bb = *(const float4*)&b[c0];
    int g0 = blockIdx.x * 32 + ry;
    int g1 = g0 + 16;
    float r0x = fmaxf(a0x + bb.x, 0.f), r0y = fmaxf(a0y + bb.y, 0.f);
    float r0z = fmaxf(a0z + bb.z, 0.f), r0w = fmaxf(a0w + bb.w, 0.f);
    float r1x = fmaxf(a1x + bb.x, 0.f), r1y = fmaxf(a1y + bb.y, 0.f);
    float r1z = fmaxf(a1z + bb.z, 0.f), r1w = fmaxf(a1w + bb.w, 0.f);
    if (g0 < NN) {
        if (FINAL) {
            *(float4*)&outf[g0 * DD + c0] = make_float4(r0x, r0y, r0z, r0w);
        } else {
            float sc = dinv[g0];
            __half h[4];
            h[0] = __float2half_rn(sc * r0x); h[1] = __float2half_rn(sc * r0y);
            h[2] = __float2half_rn(sc * r0z); h[3] = __float2half_rn(sc * r0w);
            *(uint2*)&acth[g0 * DD + c0] = *(uint2*)h;
        }
    }
    if (g1 < NN) {
        if (FINAL) {
            *(float4*)&outf[g1 * DD + c0] = make_float4(r1x, r1y, r1z, r1w);
        } else {
            float sc = dinv[g1];
            __half h[4];
            h[0] = __float2half_rn(sc * r1x); h[1] = __float2half_rn(sc * r1y);
            h[2] = __float2half_rn(sc * r1z); h[3] = __float2half_rn(sc * r1w);
            *(uint2*)&acth[g1 * DD + c0] = *(uint2*)h;
        }
    }
}

// ----------------------------------------------------------------------------

extern "C" void kernel_launch(void* const* d_in, const int* in_sizes, int n_in,
                              void* d_out, int out_size, void* d_ws, size_t ws_size,
                              hipStream_t stream) {
    const float* x  = (const float*)d_in[0];
    const int*   ei = (const int*)d_in[1];
    const float* W1 = (const float*)d_in[2];
    const float* b1 = (const float*)d_in[3];
    const float* W2 = (const float*)d_in[4];
    const float* b2 = (const float*)d_in[5];
    float* out = (float*)d_out;

    // Workspace (~23.0 MB): histB, binTot, binbase, rp, dinv, col, bufA, bufB.
    // packed[] aliases bufA (EE ints = 3.2 MB <= 9.6 MB; dead before k_cvt).
    char* p = (char*)d_ws;
    int*   histB   = (int*)p;   p += ((size_t)NBIN * CB * 4 + 255) & ~(size_t)255;
    int*   binTot  = (int*)p;   p += ((size_t)NBIN * 4 + 255) & ~(size_t)255;
    int*   binbase = (int*)p;   p += ((size_t)(NBIN + 1) * 4 + 255) & ~(size_t)255;
    int*   rp      = (int*)p;   p += ((size_t)(NN + 1) * 4 + 255) & ~(size_t)255;
    float* dinv    = (float*)p; p += ((size_t)NN * 4 + 255) & ~(size_t)255;
    int*   col     = (int*)p;   p += ((size_t)EE * 4 + 255) & ~(size_t)255;
    __half* bufA   = (__half*)p; p += ((size_t)NN * DD * 2 + 255) & ~(size_t)255;
    __half* bufB   = (__half*)p;                  // N*D halves (9.6 MB)
    int*   packed  = (int*)bufA;                  // EE ints, alias

    // ---- CSR build (no global atomics, no serial scans) ----
    k_hist<<<CB, 256, 0, stream>>>(ei, histB);
    k_scan_bins<<<NBIN, 256, 0, stream>>>(histB, binTot);
    k_scan_tot<<<1, 256, 0, stream>>>(binTot, binbase);
    k_scatter_bins<<<CB, 256, 0, stream>>>(ei, histB, binbase, packed);
    k_csr<<<NBIN, 256, 0, stream>>>(packed, binbase, rp, dinv, col);

    // ---- x_h = fp16(dinv .* x) ----
    k_cvt<<<(NN * 12 + 255) / 256, 256, 0, stream>>>(x, dinv, bufA);

    // ---- layer 1 (fused): bufB = fp16(dinv .* relu(agg(bufA) @ W1 + b1)) ----
    k_fused<0><<<(NN + 31) / 32, 384, 0, stream>>>(bufA, rp, col, dinv, W1, b1,
                                                   bufB, nullptr);

    // ---- layer 2 (fused): d_out = relu(agg(bufB) @ W2 + b2) ----
    k_fused<1><<<(NN + 31) / 32, 384, 0, stream>>>(bufB, rp, col, dinv, W2, b2,
                                                   nullptr, out);
}